// Round 9
// baseline (195.184 us; speedup 1.0000x reference)
//
#include <hip/hip_runtime.h>
#include <hip/hip_bf16.h>

#define NN 3072
#define CCC 16
#define HH 128
#define KTOP 4
#define NCLS 455   // C(15,3)
#define NUP 120
#define EPSF 1e-5f

// ---------------- ws layout (float offsets) ----------------
#define OFF_F       0
#define SZ_F        (16*NCLS*HH)            // 931840
#define OFF_CNT     (OFF_F + SZ_F)
#define SZ_CNT      (16*NCLS)
#define OFF_SUMS    (OFF_CNT + SZ_CNT)
#define SZ_SUMS     32
#define OFF_NCNT    (OFF_SUMS + SZ_SUMS)    // int nodeCnt[16*16] (64B-padded)
#define SZ_NCNT     256
#define ZERO_FLOATS (OFF_NCNT + SZ_NCNT)    // 939408 floats zeroed by k_cvt
#define OFF_LOGITS  ZERO_FLOATS
#define SZ_LOGITS   (NN*CCC)
#define OFF_COLS    (OFF_LOGITS + SZ_LOGITS)
#define SZ_E        (NN*KTOP)
#define OFF_RANKS   (OFF_COLS + SZ_E)
#define OFF_FISEL   (OFF_RANKS + SZ_E)
#define OFF_NLIST   (OFF_FISEL + SZ_E)
#define SZ_NLIST    (16*NN)
#define OFF_UP      (OFF_NLIST + SZ_NLIST)     // 16*120*128
#define SZ_UP       (16*NUP*HH)
#define OFF_AGG     (OFF_UP + SZ_UP)
#define OFF_HC      (OFF_AGG + SZ_F)
#define SZ_HC       (NN*KTOP*HH)
#define OFF_HALF    (OFF_HC + SZ_HC)
#define HOFF_W1H    0
#define HOFF_W1L    16384
#define HOFF_WLH    32768
#define HOFF_WRH    (32768 + 262144)
#define CVT_TOTAL   (16384 + 262144 + 262144)

typedef _Float16 h8 __attribute__((ext_vector_type(8)));
typedef float    f4 __attribute__((ext_vector_type(4)));

__device__ __forceinline__ int C2i(int x){ return x*(x-1)/2; }
__device__ __forceinline__ int C3i(int x){ return x*(x-1)*(x-2)/6; }

__device__ __forceinline__ unsigned decode_mask(int r){
  int c = 2; while (c < 14 && C3i(c+1) <= r) c++;
  int rem = r - C3i(c);
  int b = 1; while (b < c-1 && C2i(b+1) <= rem) b++;
  int a = rem - C2i(b);
  return (1u<<a) | (1u<<b) | (1u<<c);
}

#define MT 64

// ======== stage 0: zero accumulators + weight conversion to f16 (one dispatch) ========
__global__ __launch_bounds__(256) void k_cvt(const float* __restrict__ W1,
    const float* __restrict__ Wl, const float* __restrict__ Wr,
    _Float16* __restrict__ hbase, float* __restrict__ ws){
  int i = blockIdx.x*256 + threadIdx.x;
  if (i < ZERO_FLOATS) ws[i] = 0.f;
  if (i < 16384){
    float x = W1[i];
    _Float16 h = (_Float16)x;
    hbase[HOFF_W1H + i] = h;
    hbase[HOFF_W1L + i] = (_Float16)(x - (float)h);
  }
  int j = i - 16384;
  if (j >= 0 && j < 262144) hbase[HOFF_WLH + j] = (_Float16)Wl[j];
  int k2 = i - (16384 + 262144);
  if (k2 >= 0 && k2 < 262144) hbase[HOFF_WRH + k2] = (_Float16)Wr[k2];
}

// ================= stage A: z=relu(X@W1^T+b1); LN; logit=zn.W2+b2 =================
// MFMA 16x16x32 f16, 2-way hi/lo split for f32-grade precision. No LDS/barriers.
__global__ __launch_bounds__(256) void k_logits(const float* __restrict__ X,
    const _Float16* __restrict__ W1h, const _Float16* __restrict__ W1l,
    const float* __restrict__ b1, const float* __restrict__ ln_g,
    const float* __restrict__ ln_b, const float* __restrict__ W2,
    const float* __restrict__ b2, float* __restrict__ logits){
  int t = threadIdx.x;
  int w = t >> 6;
  int lane = t & 63;
  int l15 = lane & 15, quad = lane >> 4;
  int base = blockIdx.x * MT;
  int mA = base + 16*w + l15;

  const float* xrow = X + (size_t)mA*HH;
  h8 ah[4], al[4];
  #pragma unroll
  for (int c=0;c<4;++c){
    float4 u = *(const float4*)(xrow + c*32 + quad*8);
    float4 v = *(const float4*)(xrow + c*32 + quad*8 + 4);
    float xv[8] = {u.x,u.y,u.z,u.w,v.x,v.y,v.z,v.w};
    #pragma unroll
    for (int j=0;j<8;++j){
      _Float16 hi = (_Float16)xv[j];
      ah[c][j] = hi;
      al[c][j] = (_Float16)(xv[j] - (float)hi);
    }
  }

  f4 acc[8];
  #pragma unroll
  for (int nt=0;nt<8;++nt) acc[nt] = (f4){0.f,0.f,0.f,0.f};

  #pragma unroll
  for (int c=0;c<4;++c){
    #pragma unroll
    for (int nt=0;nt<8;++nt){
      int o = nt*16 + l15;
      h8 bh  = *(const h8*)(W1h + (size_t)o*HH + c*32 + quad*8);
      h8 bl_ = *(const h8*)(W1l + (size_t)o*HH + c*32 + quad*8);
      acc[nt] = __builtin_amdgcn_mfma_f32_16x16x32_f16(ah[c], bh,  acc[nt], 0,0,0);
      acc[nt] = __builtin_amdgcn_mfma_f32_16x16x32_f16(al[c], bh,  acc[nt], 0,0,0);
      acc[nt] = __builtin_amdgcn_mfma_f32_16x16x32_f16(ah[c], bl_, acc[nt], 0,0,0);
      acc[nt] = __builtin_amdgcn_mfma_f32_16x16x32_f16(al[c], bl_, acc[nt], 0,0,0);
    }
  }

  float bv[8], gv[8], lv[8], wv[8];
  #pragma unroll
  for (int nt=0;nt<8;++nt){
    int o = nt*16 + l15;
    bv[nt]=b1[o]; gv[nt]=ln_g[o]; lv[nt]=ln_b[o]; wv[nt]=W2[o];
  }
  float b2v = b2[0];
  #pragma unroll
  for (int r=0;r<4;++r){
    float z[8];
    float s1=0.f, s2=0.f;
    #pragma unroll
    for (int nt=0;nt<8;++nt){
      float zz = acc[nt][r] + bv[nt];
      zz = zz>0.f ? zz : 0.f;
      z[nt] = zz; s1 += zz; s2 += zz*zz;
    }
    #pragma unroll
    for (int m=1;m<16;m<<=1){ s1 += __shfl_xor(s1,m); s2 += __shfl_xor(s2,m); }
    float mu = s1/(float)HH;
    float var = s2/(float)HH - mu*mu;
    float rs = 1.0f/sqrtf(var+EPSF);
    float s3 = 0.f;
    #pragma unroll
    for (int nt=0;nt<8;++nt){
      float zn = (z[nt]-mu)*rs*gv[nt] + lv[nt];
      s3 += zn*wv[nt];
    }
    #pragma unroll
    for (int m=1;m<16;m<<=1) s3 += __shfl_xor(s3,m);
    if (l15 == 0) logits[base + 16*w + quad*4 + r] = s3 + b2v;
  }
}

// ================= stage B: softmax fi, top-4, class ranks, node lists =================
__global__ __launch_bounds__(256) void k_topk(const float* __restrict__ logits,
    int* __restrict__ cols, int* __restrict__ ranks, float* __restrict__ fiSel,
    int* __restrict__ nodeCnt, int* __restrict__ nodeList){
  __shared__ int lcnt[CCC];
  __shared__ int lbase[CCC];
  int t = threadIdx.x;
  if (t < CCC) lcnt[t] = 0;
  __syncthreads();
  int n = blockIdx.x*256 + t;
  float l[CCC];
  #pragma unroll
  for (int c=0;c<CCC;++c) l[c] = logits[n*CCC+c];
  unsigned mask = 0;
  #pragma unroll
  for (int k=0;k<KTOP;++k){
    float best = -3e38f; int bi = 0;
    #pragma unroll
    for (int c=0;c<CCC;++c){
      bool taken = (mask>>c)&1u;
      if (!taken && l[c] > best){ best = l[c]; bi = c; }
    }
    mask |= 1u<<bi;
  }
  float m = -3e38f;
  #pragma unroll
  for (int c=0;c<CCC;++c) m = l[c]>m ? l[c] : m;
  float s = 0.f;
  #pragma unroll
  for (int c=0;c<CCC;++c) s += expf(l[c]-m);
  float inv = 1.0f/s;
  int mycis[KTOP], mypos[KTOP];
  unsigned m2 = mask;
  for (int j=0;j<KTOP;++j){
    int ci = __ffs(m2)-1; m2 &= m2-1u;
    unsigned rest = mask & ~(1u<<ci);
    int v[3]; unsigned r2 = rest;
    #pragma unroll
    for (int q=0;q<3;++q){ int col = __ffs(r2)-1; r2 &= r2-1u; v[q] = col - (col>ci ? 1:0); }
    int rank = C3i(v[2]) + C2i(v[1]) + v[0];
    int e4 = n*KTOP + j;
    cols[e4] = ci; ranks[e4] = rank;
    fiSel[e4] = expf(l[ci]-m)*inv;
    mycis[j] = ci;
    mypos[j] = atomicAdd(&lcnt[ci], 1);
  }
  __syncthreads();
  if (t < CCC) lbase[t] = atomicAdd(&nodeCnt[t*16], lcnt[t]);
  __syncthreads();
  #pragma unroll
  for (int j=0;j<KTOP;++j){
    int ci = mycis[j];
    nodeList[ci*NN + lbase[ci] + mypos[j]] = n*KTOP + j;
  }
}

// ================= stage C: class feature sums (global atomics, 6144 blocks) ==========
__global__ __launch_bounds__(256) void k_accF(const float* __restrict__ X,
    const int* __restrict__ cols, const int* __restrict__ ranks,
    const float* __restrict__ fiSel, float* __restrict__ F, float* __restrict__ cnt){
  int e = blockIdx.x*2 + (threadIdx.x>>7);
  int h = threadIdx.x & 127;
  int ci = cols[e], rank = ranks[e];
  float fi = fiSel[e];
  int n = e >> 2;
  float v = X[(n*CCC+ci)*HH + h] * fi;
  atomicAdd(&F[(ci*NCLS+rank)*HH + h], v);
  if (h==0) atomicAdd(&cnt[ci*NCLS+rank], 1.0f);
}

// ================= stage D1a: pairs P_xy = sum_z F[{x,y,z}] (13 direct summands) =======
__global__ __launch_bounds__(128) void k_pairs(const float* __restrict__ F, float* __restrict__ UP){
  int t = threadIdx.x;
  int p = blockIdx.x, ci = blockIdx.y;
  int pb = 1; while (pb < 14 && C2i(pb+1) <= p) pb++;
  int pa = p - C2i(pb);
  const float* Fc = F + (size_t)ci*NCLS*HH;
  float acc = 0.f;
  #pragma unroll
  for (int z = 0; z < 15; ++z){
    if (z == pa || z == pb) continue;
    int lo, mid, hi;
    if (z < pa){ lo = z;  mid = pa; hi = pb; }
    else if (z < pb){ lo = pa; mid = z;  hi = pb; }
    else { lo = pa; mid = pb; hi = z; }
    int rank = C3i(hi) + C2i(mid) + lo;
    acc += Fc[(size_t)rank*HH + t];
  }
  UP[((size_t)ci*NUP + 15 + p)*HH + t] = acc;
}

// ================= stage D1b: singles U_x = 0.5 * sum_{y!=x} P_xy =================
__global__ __launch_bounds__(128) void k_singles(float* __restrict__ UP){
  int t = threadIdx.x;
  int x = blockIdx.x, ci = blockIdx.y;
  const float* Pc = UP + ((size_t)ci*NUP + 15)*HH;
  float acc = 0.f;
  #pragma unroll
  for (int y = 0; y < 15; ++y){
    if (y == x) continue;
    int lo = x < y ? x : y, hi = x < y ? y : x;
    int pi = C2i(hi) + lo;
    acc += Pc[(size_t)pi*HH + t];
  }
  UP[((size_t)ci*NUP + x)*HH + t] = 0.5f*acc;
}

// ================= stage D2: per-class agg via inclusion-exclusion (+deg fused) =======
__global__ __launch_bounds__(128) void k_as(const float* __restrict__ F,
    const float* __restrict__ UP, const float* __restrict__ cnt, float* __restrict__ agg){
  __shared__ unsigned tm[NCLS];
  __shared__ float dred[2];
  int t = threadIdx.x;
  for (int i=t;i<NCLS;i+=128) tm[i] = decode_mask(i);
  __syncthreads();
  int r = blockIdx.x, ci = blockIdx.y;
  unsigned m = tm[r];
  float d = 0.f;
  const float* cc = cnt + ci*NCLS;
  for (int tp=t; tp<NCLS; tp+=128)
    if (m & tm[tp]) d += cc[tp];
  #pragma unroll
  for (int mm=1; mm<64; mm<<=1) d += __shfl_xor(d, mm);
  if ((t&63)==0) dred[t>>6] = d;
  __syncthreads();
  float invd = 1.0f / fmaxf(dred[0]+dred[1], 1.0f);
  int c = 2; while (c < 14 && C3i(c+1) <= r) c++;
  int rem = r - C3i(c);
  int b = 1; while (b < c-1 && C2i(b+1) <= rem) b++;
  int a = rem - C2i(b);
  const float* U = UP + ci*NUP*HH;
  int pab = 15 + C2i(b) + a;
  int pac = 15 + C2i(c) + a;
  int pbc = 15 + C2i(c) + b;
  float v = U[a*HH+t] + U[b*HH+t] + U[c*HH+t]
          - U[pab*HH+t] - U[pac*HH+t] - U[pbc*HH+t]
          + F[(ci*NCLS+r)*HH + t];
  agg[(ci*NCLS+r)*HH + t] = v * invd;
}

// ================= stage E1: AggWl = Agg @ Wl^T + bl (per class, in-place, f16 MFMA) ====
__global__ __launch_bounds__(256) void k_aggwl(float* __restrict__ agg,
    const _Float16* __restrict__ Wlh, const float* __restrict__ bl){
  int t = threadIdx.x;
  int w = t >> 6;
  int lane = t & 63;
  int l15 = lane & 15, quad = lane >> 4;
  int ci = blockIdx.y;
  int base = blockIdx.x * MT;
  int rowA = base + 16*w + l15; if (rowA > NCLS-1) rowA = NCLS-1;

  const float* arow = agg + ((size_t)ci*NCLS + rowA)*HH;
  h8 af[4];
  #pragma unroll
  for (int c=0;c<4;++c){
    float4 u = *(const float4*)(arow + c*32 + quad*8);
    float4 v = *(const float4*)(arow + c*32 + quad*8 + 4);
    float xv[8] = {u.x,u.y,u.z,u.w,v.x,v.y,v.z,v.w};
    #pragma unroll
    for (int j=0;j<8;++j) af[c][j] = (_Float16)xv[j];
  }

  f4 acc[8];
  #pragma unroll
  for (int nt=0;nt<8;++nt) acc[nt] = (f4){0.f,0.f,0.f,0.f};

  const _Float16* Wc = Wlh + (size_t)ci*HH*HH;
  #pragma unroll
  for (int c=0;c<4;++c){
    #pragma unroll
    for (int nt=0;nt<8;++nt){
      int o = nt*16 + l15;
      h8 bh = *(const h8*)(Wc + (size_t)o*HH + c*32 + quad*8);
      acc[nt] = __builtin_amdgcn_mfma_f32_16x16x32_f16(af[c], bh, acc[nt], 0,0,0);
    }
  }
  #pragma unroll
  for (int r=0;r<4;++r){
    int row2 = base + 16*w + quad*4 + r;
    if (row2 < NCLS){
      float* drow = agg + ((size_t)ci*NCLS + row2)*HH;
      #pragma unroll
      for (int nt=0;nt<8;++nt){
        int o = nt*16 + l15;
        drow[o] = acc[nt][r] + bl[ci*HH + o];
      }
    }
  }
}

// ================= stage E2: hc = relu(AggWl[class] + fi*X @ Wr^T) (f16 MFMA) =========
__global__ __launch_bounds__(256) void k_hc2(const float* __restrict__ X,
    const _Float16* __restrict__ Wrh,
    const int* __restrict__ ranks, const float* __restrict__ fiSel,
    const int* __restrict__ nodeCnt, const int* __restrict__ nodeList,
    const float* __restrict__ aggwl, float* __restrict__ hcBuf, float* __restrict__ sums){
  int ci = blockIdx.y;
  int cntc = nodeCnt[ci*16];
  int base = blockIdx.x * MT;
  if (base >= cntc) return;
  __shared__ float rb[8];
  int t = threadIdx.x;
  int w = t >> 6;
  int lane = t & 63;
  int l15 = lane & 15, quad = lane >> 4;

  int pA = base + 16*w + l15;
  float fi = 0.f; int nA = 0;
  if (pA < cntc){
    int e = nodeList[ci*NN + pA];
    fi = fiSel[e]; nA = e >> 2;
  }
  const float* xrow = X + ((size_t)nA*CCC + ci)*HH;
  h8 af[4];
  #pragma unroll
  for (int c=0;c<4;++c){
    float4 u = *(const float4*)(xrow + c*32 + quad*8);
    float4 v = *(const float4*)(xrow + c*32 + quad*8 + 4);
    float xv[8] = {u.x,u.y,u.z,u.w,v.x,v.y,v.z,v.w};
    #pragma unroll
    for (int j=0;j<8;++j) af[c][j] = (_Float16)(xv[j]*fi);
  }

  f4 acc[8];
  #pragma unroll
  for (int nt=0;nt<8;++nt) acc[nt] = (f4){0.f,0.f,0.f,0.f};

  const _Float16* Wc = Wrh + (size_t)ci*HH*HH;
  #pragma unroll
  for (int c=0;c<4;++c){
    #pragma unroll
    for (int nt=0;nt<8;++nt){
      int o = nt*16 + l15;
      h8 bh = *(const h8*)(Wc + (size_t)o*HH + c*32 + quad*8);
      acc[nt] = __builtin_amdgcn_mfma_f32_16x16x32_f16(af[c], bh, acc[nt], 0,0,0);
    }
  }

  float s1 = 0.f, s2 = 0.f;
  #pragma unroll
  for (int r=0;r<4;++r){
    int pD = base + 16*w + quad*4 + r;
    int e2 = -1, rk2 = 0;
    if (pD < cntc){ e2 = nodeList[ci*NN + pD]; rk2 = ranks[e2]; }
    if (e2 >= 0){
      const float* G = aggwl + ((size_t)ci*NCLS + rk2)*HH;
      float* drow = hcBuf + (size_t)e2*HH;
      #pragma unroll
      for (int nt=0;nt<8;++nt){
        int o = nt*16 + l15;
        float vv = acc[nt][r] + G[o];
        vv = vv>0.f ? vv : 0.f;
        drow[o] = vv;
        s1 += vv; s2 += vv*vv;
      }
    }
  }
  #pragma unroll
  for (int m=1;m<64;m<<=1){ s1 += __shfl_xor(s1,m); s2 += __shfl_xor(s2,m); }
  if (lane == 0){ rb[w] = s1; rb[4+w] = s2; }
  __syncthreads();
  if (t==0){
    atomicAdd(&sums[ci],    rb[0]+rb[1]+rb[2]+rb[3]);
    atomicAdd(&sums[16+ci], rb[4]+rb[5]+rb[6]+rb[7]);
  }
}

// ================= stage F: masked mean/var normalize, write output =================
__global__ __launch_bounds__(256) void k_out(const float* __restrict__ hcBuf,
    const int* __restrict__ cols, const int* __restrict__ nodeCnt,
    const float* __restrict__ sums, float* __restrict__ out){
  int idx = blockIdx.x*256 + threadIdx.x;
  int e = idx >> 7;
  int ci = cols[e];
  float cntf = (float)nodeCnt[ci*16];
  float nel = fmaxf(cntf * (float)HH, 1.0f);
  float mu = sums[ci]/nel;
  float var = sums[16+ci]/nel - mu*mu;
  out[idx] = (hcBuf[idx]-mu)/sqrtf(var+EPSF);
}

extern "C" void kernel_launch(void* const* d_in, const int* in_sizes, int n_in,
                              void* d_out, int out_size, void* d_ws, size_t ws_size,
                              hipStream_t stream){
  const float* X    = (const float*)d_in[0];
  const float* W1   = (const float*)d_in[1];
  const float* b1   = (const float*)d_in[2];
  const float* ln_g = (const float*)d_in[3];
  const float* ln_b = (const float*)d_in[4];
  const float* W2   = (const float*)d_in[5];
  const float* b2   = (const float*)d_in[6];
  const float* Wl   = (const float*)d_in[7];
  const float* bl   = (const float*)d_in[8];
  const float* Wr   = (const float*)d_in[9];
  float* ws = (float*)d_ws;
  float* F      = ws + OFF_F;
  float* cnt    = ws + OFF_CNT;
  float* sums   = ws + OFF_SUMS;
  int*   nodeCnt= (int*)(ws + OFF_NCNT);
  float* logits = ws + OFF_LOGITS;
  int*   cols   = (int*)(ws + OFF_COLS);
  int*   ranks  = (int*)(ws + OFF_RANKS);
  float* fiSel  = ws + OFF_FISEL;
  int*   nodeList=(int*)(ws + OFF_NLIST);
  float* UP     = ws + OFF_UP;
  float* agg    = ws + OFF_AGG;
  float* hcBuf  = ws + OFF_HC;
  _Float16* hbase = (_Float16*)(ws + OFF_HALF);
  float* out    = (float*)d_out;

  int cvtGrid = (ZERO_FLOATS > CVT_TOTAL ? ZERO_FLOATS : CVT_TOTAL + 255) / 256 + 1;
  k_cvt    <<<dim3(cvtGrid), dim3(256), 0, stream>>>(W1, Wl, Wr, hbase, ws);
  k_logits <<<dim3(NN*CCC/MT), dim3(256), 0, stream>>>(X, hbase+HOFF_W1H, hbase+HOFF_W1L,
                                                       b1, ln_g, ln_b, W2, b2, logits);
  k_topk   <<<dim3(NN/256), dim3(256), 0, stream>>>(logits, cols, ranks, fiSel, nodeCnt, nodeList);
  k_accF   <<<dim3(NN*KTOP/2), dim3(256), 0, stream>>>(X, cols, ranks, fiSel, F, cnt);
  k_pairs  <<<dim3(105,16), dim3(128), 0, stream>>>(F, UP);
  k_singles<<<dim3(15,16), dim3(128), 0, stream>>>(UP);
  k_as     <<<dim3(NCLS,16), dim3(128), 0, stream>>>(F, UP, cnt, agg);
  k_aggwl  <<<dim3((NCLS+MT-1)/MT,16), dim3(256), 0, stream>>>(agg, hbase+HOFF_WLH, bl);
  k_hc2    <<<dim3((NN/MT),16), dim3(256), 0, stream>>>(X, hbase+HOFF_WRH, ranks, fiSel,
                                                        nodeCnt, nodeList, agg, hcBuf, sums);
  k_out    <<<dim3(NN*KTOP*HH/256), dim3(256), 0, stream>>>(hcBuf, cols, nodeCnt, sums, out);
}